// Round 5
// baseline (1073.057 us; speedup 1.0000x reference)
//
#include <hip/hip_runtime.h>
#include <cstdint>
#include <cstddef>

#define NB 8
#define NPG0 6000
#define N0 48000
#define NE 384000
#define KP1 3600
#define KP2 2160
#define KP3 1080

typedef __attribute__((ext_vector_type(8))) short short8;
typedef __attribute__((ext_vector_type(4))) float f32x4;
typedef __attribute__((ext_vector_type(4))) unsigned int u32x4;

__device__ inline ushort f2bf(float v) {
  unsigned u = __float_as_uint(v);
  u += 0x7FFF + ((u >> 16) & 1);
  return (ushort)(u >> 16);
}
__device__ inline float bf2f(ushort h) { return __uint_as_float(((unsigned)h) << 16); }

__device__ __forceinline__ void glds16(const void* g, void* l) {
  __builtin_amdgcn_global_load_lds(
      (const __attribute__((address_space(1))) unsigned int*)g,
      (__attribute__((address_space(3))) unsigned int*)l, 16, 0, 0);
}

// ============ split fp32 -> bf16 hi/lo ============
__global__ void split_kernel(const float* __restrict__ x, ushort* __restrict__ hi,
                             ushort* __restrict__ lo, size_t n4) {
  size_t i = (size_t)blockIdx.x * blockDim.x + threadIdx.x;
  size_t stride = (size_t)gridDim.x * blockDim.x;
  for (; i < n4; i += stride) {
    float4 v = ((const float4*)x)[i];
    ushort4 h, l;
    h.x = f2bf(v.x); l.x = f2bf(v.x - bf2f(h.x));
    h.y = f2bf(v.y); l.y = f2bf(v.y - bf2f(h.y));
    h.z = f2bf(v.z); l.z = f2bf(v.z - bf2f(h.z));
    h.w = f2bf(v.w); l.w = f2bf(v.w - bf2f(h.w));
    ((ushort4*)hi)[i] = h;
    ((ushort4*)lo)[i] = l;
  }
}

// ============ W[K,N] fp32 -> WT hi/lo bf16 [N,K] ============
__global__ void wsplit_kernel(const float* __restrict__ W, ushort* __restrict__ hiT,
                              ushort* __restrict__ loT, int K, int N) {
  __shared__ float tile[32][33];
  int k0 = blockIdx.y * 32, n0 = blockIdx.x * 32;
  int tx = threadIdx.x;
  for (int dy = threadIdx.y; dy < 32; dy += 8)
    tile[dy][tx] = W[(size_t)(k0 + dy) * N + n0 + tx];
  __syncthreads();
  for (int dy = threadIdx.y; dy < 32; dy += 8) {
    float v = tile[tx][dy];
    ushort h = f2bf(v);
    ushort l = f2bf(v - bf2f(h));
    hiT[(size_t)(n0 + dy) * K + k0 + tx] = h;
    loT[(size_t)(n0 + dy) * K + k0 + tx] = l;
  }
}

// ============ GEMM: split-bf16 MFMA, 128x128 tile, BK=32, global_load_lds ====
// LDS layout per buffer: 4 regions (Ahi,Alo,Bhi,Blo) x 512 chunks(16B).
// Chunk (r,q) holds global k-chunk (r, q^swz(r)), swz(r)=(r&3)^((r>>2)&3) —
// achieved by pre-swizzling the per-lane GLOBAL address (LDS dest stays linear).
__global__ __launch_bounds__(256) void gemm_split(
    const ushort* __restrict__ Ahi, const ushort* __restrict__ Alo,
    const ushort* __restrict__ BThi, const ushort* __restrict__ BTlo,
    float* __restrict__ C, int M, int K, int N, int mblocks) {
  __shared__ u32x4 lds4[4096];  // 2 x 32KB
  const int tid = threadIdx.x;
  const int lane = tid & 63;
  const int w = tid >> 6;       // wave id = staging region
  const int mblk = blockIdx.x % mblocks;
  const int nblk = blockIdx.x / mblocks;
  const int bm = mblk * 128, bn = nblk * 128;
  const int wr = w >> 1, wc = w & 1;

  // staging: wave w stages region w; instruction i covers rows i*16+(lane>>2)
  const ushort* srcp[8];
  {
    const ushort* base = (w == 0) ? Ahi : (w == 1) ? Alo : (w == 2) ? BThi : BTlo;
    #pragma unroll
    for (int i = 0; i < 8; ++i) {
      int r = i * 16 + (lane >> 2);
      int swz = (r & 3) ^ ((r >> 2) & 3);
      int pcs = (lane & 3) ^ swz;
      int grow = (w < 2) ? min(bm + r, M - 1) : (bn + r);
      srcp[i] = base + (size_t)grow * K + pcs * 8;
    }
  }

  f32x4 acc[4][4];
#pragma unroll
  for (int m = 0; m < 4; ++m)
#pragma unroll
    for (int n = 0; n < 4; ++n) acc[m][n] = (f32x4){0.f, 0.f, 0.f, 0.f};

  const int nk = K >> 5;
  const int kb = lane >> 4;
  const int l15 = lane & 15;

  // prologue: stage tile 0 into buf 0
#pragma unroll
  for (int i = 0; i < 8; ++i) glds16(srcp[i], &lds4[w * 512 + i * 64]);
  __syncthreads();

  int cur = 0;
  for (int t = 0; t < nk; ++t) {
    if (t + 1 < nk) {
      int nb = (cur ^ 1) * 2048;
#pragma unroll
      for (int i = 0; i < 8; ++i)
        glds16(srcp[i] + (size_t)(t + 1) * 32, &lds4[nb + w * 512 + i * 64]);
    }
    const int bb = cur * 2048;
    short8 bh[4], bl[4];
#pragma unroll
    for (int n = 0; n < 4; ++n) {
      int rB = wc * 64 + n * 16 + l15;
      int swz = (rB & 3) ^ ((rB >> 2) & 3);
      int ch = rB * 4 + (kb ^ swz);
      bh[n] = *(const short8*)&lds4[bb + 1024 + ch];
      bl[n] = *(const short8*)&lds4[bb + 1536 + ch];
    }
#pragma unroll
    for (int m = 0; m < 4; ++m) {
      int rA = wr * 64 + m * 16 + l15;
      int swz = (rA & 3) ^ ((rA >> 2) & 3);
      int ch = rA * 4 + (kb ^ swz);
      short8 ah = *(const short8*)&lds4[bb + ch];
      short8 al = *(const short8*)&lds4[bb + 512 + ch];
#pragma unroll
      for (int n = 0; n < 4; ++n) {
        acc[m][n] = __builtin_amdgcn_mfma_f32_16x16x32_bf16(ah, bh[n], acc[m][n], 0, 0, 0);
        acc[m][n] = __builtin_amdgcn_mfma_f32_16x16x32_bf16(ah, bl[n], acc[m][n], 0, 0, 0);
        acc[m][n] = __builtin_amdgcn_mfma_f32_16x16x32_bf16(al, bh[n], acc[m][n], 0, 0, 0);
      }
    }
    __syncthreads();
    cur ^= 1;
  }

#pragma unroll
  for (int m = 0; m < 4; ++m) {
    int gr0 = bm + wr * 64 + m * 16 + ((lane >> 4) << 2);
#pragma unroll
    for (int j = 0; j < 4; ++j) {
      int gr = gr0 + j;
      if (gr < M) {
#pragma unroll
        for (int n = 0; n < 4; ++n) {
          C[(size_t)gr * N + bn + wc * 64 + n * 16 + (lane & 15)] = acc[m][n][j];
        }
      }
    }
  }
}

// ---------------- CSR build ----------------
__global__ void edge_count_kernel(const int* __restrict__ col, const float* __restrict__ w,
                                  int E, int* __restrict__ counts) {
  int i = blockIdx.x * blockDim.x + threadIdx.x;
  if (i >= E) return;
  if (w && !(w[i] > 0.f)) return;
  atomicAdd(&counts[col[i]], 1);
}

// scan + dinv fused
__global__ __launch_bounds__(1024) void scan_kernel(const int* __restrict__ counts,
                                                    int* __restrict__ offsets,
                                                    float* __restrict__ dinv, int n) {
  __shared__ int wsum[16];
  int tid = threadIdx.x;
  int per = (n + 1023) / 1024;
  int beg = tid * per;
  int end = min(beg + per, n);
  int s = 0;
  for (int i = beg; i < end; ++i) s += counts[i];
  int lane = tid & 63, wid = tid >> 6;
  int v = s;
  for (int off = 1; off < 64; off <<= 1) {
    int t = __shfl_up(v, off);
    if (lane >= off) v += t;
  }
  if (lane == 63) wsum[wid] = v;
  __syncthreads();
  if (wid == 0) {
    int wv = (lane < 16) ? wsum[lane] : 0;
    for (int off = 1; off < 16; off <<= 1) {
      int t = __shfl_up(wv, off);
      if (lane >= off) wv += t;
    }
    if (lane < 16) wsum[lane] = wv;
  }
  __syncthreads();
  int base = (v - s) + (wid > 0 ? wsum[wid - 1] : 0);
  int run = base;
  for (int i = beg; i < end; ++i) {
    offsets[i] = run;
    int c = counts[i];
    run += c;
    dinv[i] = (c > 0) ? rsqrtf((float)c) : 0.f;
  }
  if (tid == 1023) offsets[n] = run;
}

__global__ void csr_fill_kernel(const int* __restrict__ row, const int* __restrict__ col,
                                const float* __restrict__ w, int E,
                                const int* __restrict__ offsets, int* __restrict__ fill,
                                int* __restrict__ csr_src) {
  int i = blockIdx.x * blockDim.x + threadIdx.x;
  if (i >= E) return;
  if (w && !(w[i] > 0.f)) return;
  int c = col[i];
  int pos = offsets[c] + atomicAdd(&fill[c], 1);
  csr_src[pos] = row[i];
}

// ---------------- GCN gather: wave per node, graph-per-XCD swizzle ----------------
__global__ __launch_bounds__(256) void gcn_gather_kernel(
    const float* __restrict__ G, const int* __restrict__ offsets,
    const int* __restrict__ csr_src, const float* __restrict__ dinv,
    const float* __restrict__ bias, float* __restrict__ out, int C, int n, int npg) {
  int wid = threadIdx.x >> 6, lane = threadIdx.x & 63;
  int g = blockIdx.x & 7;
  int local = blockIdx.x >> 3;
  int t = g * npg + local * 4 + wid;
  if (t >= n) return;
  int beg = offsets[t], end = offsets[t + 1];
  float dt = dinv[t];
  bool two = (C == 512);
  float4 acc0 = make_float4(0.f, 0.f, 0.f, 0.f);
  float4 acc1 = make_float4(0.f, 0.f, 0.f, 0.f);
  int e = beg;
  for (; e + 2 <= end; e += 2) {
    int s0 = csr_src[e], s1 = csr_src[e + 1];
    float d0 = dinv[s0], d1 = dinv[s1];
    const float4* h0 = (const float4*)(G + (size_t)s0 * C);
    const float4* h1 = (const float4*)(G + (size_t)s1 * C);
    float4 a0 = h0[lane];
    float4 b0 = h1[lane];
    acc0.x += d0 * a0.x; acc0.y += d0 * a0.y; acc0.z += d0 * a0.z; acc0.w += d0 * a0.w;
    acc0.x += d1 * b0.x; acc0.y += d1 * b0.y; acc0.z += d1 * b0.z; acc0.w += d1 * b0.w;
    if (two) {
      float4 a1 = h0[lane + 64];
      float4 b1 = h1[lane + 64];
      acc1.x += d0 * a1.x; acc1.y += d0 * a1.y; acc1.z += d0 * a1.z; acc1.w += d0 * a1.w;
      acc1.x += d1 * b1.x; acc1.y += d1 * b1.y; acc1.z += d1 * b1.z; acc1.w += d1 * b1.w;
    }
  }
  if (e < end) {
    int s0 = csr_src[e];
    float d0 = dinv[s0];
    const float4* h0 = (const float4*)(G + (size_t)s0 * C);
    float4 a0 = h0[lane];
    acc0.x += d0 * a0.x; acc0.y += d0 * a0.y; acc0.z += d0 * a0.z; acc0.w += d0 * a0.w;
    if (two) {
      float4 a1 = h0[lane + 64];
      acc1.x += d0 * a1.x; acc1.y += d0 * a1.y; acc1.z += d0 * a1.z; acc1.w += d0 * a1.w;
    }
  }
  float4* op = (float4*)(out + (size_t)t * C);
  float4 b0 = bias ? ((const float4*)bias)[lane] : make_float4(0.f, 0.f, 0.f, 0.f);
  op[lane] = make_float4(dt * acc0.x + b0.x, dt * acc0.y + b0.y,
                         dt * acc0.z + b0.z, dt * acc0.w + b0.w);
  if (two) {
    op[lane + 64] = make_float4(dt * acc1.x, dt * acc1.y, dt * acc1.z, dt * acc1.w);
  }
}

// ---------------- BatchNorm stats: grid-stride float4 streaming ----------------
__global__ __launch_bounds__(256) void bn_stats_kernel(
    const float* __restrict__ h, size_t n4, int C, float* __restrict__ sums) {
  __shared__ float ls[1024];
  for (int i = threadIdx.x; i < 2 * C; i += 256) ls[i] = 0.f;
  __syncthreads();
  const int c0 = (threadIdx.x * 4) & (C - 1);
  float s0 = 0.f, s1 = 0.f, s2 = 0.f, s3 = 0.f;
  float q0 = 0.f, q1 = 0.f, q2 = 0.f, q3 = 0.f;
  size_t i = (size_t)blockIdx.x * 256 + threadIdx.x;
  const size_t stride = (size_t)gridDim.x * 256;
  for (; i < n4; i += stride) {
    float4 v = ((const float4*)h)[i];
    s0 += v.x; q0 += v.x * v.x;
    s1 += v.y; q1 += v.y * v.y;
    s2 += v.z; q2 += v.z * v.z;
    s3 += v.w; q3 += v.w * v.w;
  }
  atomicAdd(&ls[c0 + 0], s0); atomicAdd(&ls[C + c0 + 0], q0);
  atomicAdd(&ls[c0 + 1], s1); atomicAdd(&ls[C + c0 + 1], q1);
  atomicAdd(&ls[c0 + 2], s2); atomicAdd(&ls[C + c0 + 2], q2);
  atomicAdd(&ls[c0 + 3], s3); atomicAdd(&ls[C + c0 + 3], q3);
  __syncthreads();
  for (int j = threadIdx.x; j < 2 * C; j += 256) atomicAdd(&sums[j], ls[j]);
}

__global__ void bn_finalize_kernel(const float* __restrict__ sums,
                                   const float* __restrict__ g,
                                   const float* __restrict__ be,
                                   int n, int C, float* __restrict__ ss) {
  int c = blockIdx.x * blockDim.x + threadIdx.x;
  if (c >= C) return;
  float inv_n = 1.0f / (float)n;
  float mean = sums[c] * inv_n;
  float var = sums[C + c] * inv_n - mean * mean;
  var = fmaxf(var, 0.f);
  float sc = g[c] * rsqrtf(var + 1e-5f);
  ss[c] = sc;
  ss[C + c] = be[c] - mean * sc;
}

// fused BN-apply + relu + pool dot products (wave per row)
__global__ __launch_bounds__(256) void bn_dots_kernel(
    float* __restrict__ h, const float* __restrict__ ss,
    const float* __restrict__ wrel, const float* __restrict__ wroot,
    float* __restrict__ u, float* __restrict__ rr, int n, int C) {
  int wid = threadIdx.x >> 6, lane = threadIdx.x & 63;
  int v = blockIdx.x * 4 + wid;
  if (v >= n) return;
  float4* hr = (float4*)(h + (size_t)v * C);
  int nf4 = C >> 2;
  float su = 0.f, sr = 0.f;
  for (int q = lane; q < nf4; q += 64) {
    float4 x = hr[q];
    int c = q << 2;
    float4 sc = *(const float4*)&ss[c];
    float4 sh = *(const float4*)&ss[C + c];
    x.x = fmaxf(fmaf(x.x, sc.x, sh.x), 0.f);
    x.y = fmaxf(fmaf(x.y, sc.y, sh.y), 0.f);
    x.z = fmaxf(fmaf(x.z, sc.z, sh.z), 0.f);
    x.w = fmaxf(fmaf(x.w, sc.w, sh.w), 0.f);
    hr[q] = x;
    float4 w1 = *(const float4*)&wrel[c];
    float4 w2 = *(const float4*)&wroot[c];
    su += x.x * w1.x + x.y * w1.y + x.z * w1.z + x.w * w1.w;
    sr += x.x * w2.x + x.y * w2.y + x.z * w2.z + x.w * w2.w;
  }
  for (int off = 32; off > 0; off >>= 1) {
    su += __shfl_down(su, off);
    sr += __shfl_down(sr, off);
  }
  if (lane == 0) {
    u[v] = su;
    rr[v] = sr;
  }
}

__global__ void score_kernel(const float* __restrict__ u, const float* __restrict__ rr,
                             const int* __restrict__ offsets, const int* __restrict__ csr_src,
                             const float* __restrict__ pb, float* __restrict__ score, int n) {
  int i = blockIdx.x * blockDim.x + threadIdx.x;
  if (i >= n) return;
  float s = rr[i] + pb[0];
  int beg = offsets[i], end = offsets[i + 1];
  for (int e = beg; e < end; ++e) s += u[csr_src[e]];
  score[i] = s;
}

// ---------------- exact top-k via 4-pass radix select (per graph) ----------------
__global__ __launch_bounds__(1024) void topk_radix_kernel(
    const float* __restrict__ score, int npg, int K, int* __restrict__ perm) {
  __shared__ unsigned sbuf[8192];
  __shared__ int tieL[6000];
  __shared__ int hist[256];
  __shared__ int wps[4];
  __shared__ unsigned sPref;
  __shared__ int sKrem, sAbove, sSel, sTie;
  int g = blockIdx.x;
  int tid = threadIdx.x;
  for (int i = tid; i < npg; i += 1024) {
    unsigned u = __float_as_uint(score[g * npg + i]);
    sbuf[i] = (u >> 31) ? ~u : (u | 0x80000000u);
  }
  if (tid == 0) { sPref = 0; sKrem = K; sAbove = 0; sSel = 0; sTie = 0; }
  __syncthreads();

  for (int pass = 0; pass < 4; ++pass) {
    int shift = 24 - 8 * pass;
    if (tid < 256) hist[tid] = 0;
    unsigned prefLoc = sPref;
    int kRemLoc = sKrem;
    __syncthreads();
    for (int i = tid; i < npg; i += 1024) {
      unsigned k = sbuf[i];
      if (pass == 0 || (k >> (shift + 8)) == prefLoc)
        atomicAdd(&hist[(k >> shift) & 255], 1);
    }
    __syncthreads();
    int v = 0, a = 0;
    if (tid < 256) {
      a = hist[255 - tid];
      v = a;
      int lane = tid & 63;
      for (int off = 1; off < 64; off <<= 1) {
        int t2 = __shfl_up(v, off);
        if (lane >= off) v += t2;
      }
      if (lane == 63) wps[tid >> 6] = v;
    }
    __syncthreads();
    if (tid < 256) {
      int w4 = tid >> 6;
      int incl = v;
      for (int q = 0; q < w4; ++q) incl += wps[q];
      int gt = incl - a;
      if (gt < kRemLoc && kRemLoc <= incl) {
        int d = 255 - tid;
        sPref = (prefLoc << 8) | (unsigned)d;
        sAbove += gt;
        sKrem = kRemLoc - gt;
      }
    }
    __syncthreads();
  }

  unsigned T = sPref;
  int above = sAbove;
  for (int i = tid; i < npg; i += 1024) {
    unsigned k = sbuf[i];
    if (k > T) {
      int p = atomicAdd(&sSel, 1);
      perm[g * K + p] = g * npg + i;
    } else if (k == T) {
      int p = atomicAdd(&sTie, 1);
      tieL[p] = i;
    }
  }
  __syncthreads();
  int r = sKrem, tc = sTie;
  if (r == tc) {
    for (int j = tid; j < r; j += 1024) perm[g * K + above + j] = g * npg + tieL[j];
  } else {
    int p2 = 1;
    while (p2 < tc) p2 <<= 1;
    for (int i = tid; i < p2; i += 1024) sbuf[i] = (i < tc) ? (unsigned)tieL[i] : 0xFFFFFFFFu;
    __syncthreads();
    for (int k2 = 2; k2 <= p2; k2 <<= 1) {
      for (int j = k2 >> 1; j > 0; j >>= 1) {
        for (int i = tid; i < p2; i += 1024) {
          int l = i ^ j;
          if (l > i) {
            unsigned a2 = sbuf[i], b2 = sbuf[l];
            bool up = ((i & k2) == 0);
            if (up ? (a2 > b2) : (a2 < b2)) { sbuf[i] = b2; sbuf[l] = a2; }
          }
        }
        __syncthreads();
      }
    }
    for (int j = tid; j < r; j += 1024) perm[g * K + above + j] = g * npg + (int)sbuf[j];
  }
}

// pooled x -> bf16 hi/lo + inv map (fused)
__global__ void xnew_split_kernel(const float* __restrict__ h, const float* __restrict__ score,
                                  const int* __restrict__ perm, ushort* __restrict__ xhi,
                                  ushort* __restrict__ xlo, int* __restrict__ inv, int C) {
  int i = blockIdx.x;
  int old = perm[i];
  if (threadIdx.x == 0) inv[old] = i;
  float tv = tanhf(score[old]);
  const float4* src = (const float4*)(h + (size_t)old * C);
  int c4 = C >> 2;
  for (int c = threadIdx.x; c < c4; c += blockDim.x) {
    float4 v = src[c];
    v.x *= tv; v.y *= tv; v.z *= tv; v.w *= tv;
    ushort4 hh, ll;
    hh.x = f2bf(v.x); ll.x = f2bf(v.x - bf2f(hh.x));
    hh.y = f2bf(v.y); ll.y = f2bf(v.y - bf2f(hh.y));
    hh.z = f2bf(v.z); ll.z = f2bf(v.z - bf2f(hh.z));
    hh.w = f2bf(v.w); ll.w = f2bf(v.w - bf2f(hh.w));
    ((ushort4*)(xhi + (size_t)i * C))[c] = hh;
    ((ushort4*)(xlo + (size_t)i * C))[c] = ll;
  }
}

// fused: remap edges + count next-layer in-degrees
__global__ void edge_remap_count_kernel(const int* __restrict__ row, const int* __restrict__ col,
                                        const float* __restrict__ w, const int* __restrict__ inv,
                                        int E, int* __restrict__ nrow, int* __restrict__ ncol,
                                        float* __restrict__ nw, int* __restrict__ counts) {
  int i = blockIdx.x * blockDim.x + threadIdx.x;
  if (i >= E) return;
  float wv = w ? w[i] : 1.f;
  int nr = inv[row[i]];
  int nc = inv[col[i]];
  bool valid = (nr >= 0) && (nc >= 0) && (wv > 0.f);
  nrow[i] = valid ? nr : 0;
  ncol[i] = valid ? nc : 0;
  nw[i] = valid ? wv : 0.f;
  if (valid) atomicAdd(&counts[nc], 1);
}

// ---------------- readout ----------------
__global__ void final_pool_kernel(const float* __restrict__ h, float* __restrict__ dout) {
  int g = blockIdx.x;
  int c = threadIdx.x;  // 256
  const float* base = h + ((size_t)g * KP3) * 256 + c;
  float mx = -3.402823466e38f, sm = 0.f;
  for (int r = 0; r < KP3; ++r) {
    float v = base[(size_t)r * 256];
    mx = fmaxf(mx, v);
    sm += v;
  }
  dout[8 + g * 512 + c] = mx;
  dout[8 + g * 512 + 256 + c] = sm * (1.0f / (float)KP3);
}

__global__ void fc_kernel(const float* __restrict__ feat, const float* __restrict__ fcW,
                          const float* __restrict__ fcb, float* __restrict__ dout) {
  int g = blockIdx.x;
  int lane = threadIdx.x;  // 64
  float s = 0.f;
  for (int c = lane; c < 512; c += 64) s += feat[g * 512 + c] * fcW[c];
  for (int off = 32; off > 0; off >>= 1) s += __shfl_down(s, off);
  if (lane == 0) dout[g] = s + fcb[0];
}

// ---------------- host ----------------
static inline size_t alignup(size_t x) { return (x + 255) & ~(size_t)255; }

extern "C" void kernel_launch(void* const* d_in, const int* in_sizes, int n_in,
                              void* d_out, int out_size, void* d_ws, size_t ws_size,
                              hipStream_t stream) {
  (void)in_sizes; (void)n_in; (void)out_size; (void)ws_size;
  const float* x0 = (const float*)d_in[0];
  const int* ei = (const int*)d_in[1];
  const int* row0 = ei;
  const int* col0 = ei + NE;
  const float* W1 = (const float*)d_in[2];
  const float* g1 = (const float*)d_in[4];
  const float* be1 = (const float*)d_in[5];
  const float* p1rel = (const float*)d_in[6];
  const float* p1root = (const float*)d_in[7];
  const float* p1b = (const float*)d_in[8];
  const float* W2 = (const float*)d_in[9];
  const float* g2 = (const float*)d_in[11];
  const float* be2 = (const float*)d_in[12];
  const float* p2rel = (const float*)d_in[13];
  const float* p2root = (const float*)d_in[14];
  const float* p2b = (const float*)d_in[15];
  const float* W3 = (const float*)d_in[16];
  const float* g3 = (const float*)d_in[18];
  const float* be3 = (const float*)d_in[19];
  const float* p3rel = (const float*)d_in[20];
  const float* p3root = (const float*)d_in[21];
  const float* p3b = (const float*)d_in[22];
  const float* W4 = (const float*)d_in[23];
  const float* b4 = (const float*)d_in[24];
  const float* fcW = (const float*)d_in[25];
  const float* fcb = (const float*)d_in[26];
  float* out = (float*)d_out;

  char* ws = (char*)d_ws;
  size_t off = 0;
  auto alloc = [&](size_t bytes) {
    char* p = ws + off;
    off = alignup(off + bytes);
    return p;
  };
  float* RegA = (float*)alloc((size_t)N0 * 512 * 4);
  float* RegB = (float*)alloc((size_t)N0 * 512 * 4);
  ushort* Ahi = (ushort*)alloc((size_t)N0 * 512 * 2);
  ushort* Alo = (ushort*)alloc((size_t)N0 * 512 * 2);
  int* rowA = (int*)alloc((size_t)NE * 4);
  int* colA = (int*)alloc((size_t)NE * 4);
  float* wA = (float*)alloc((size_t)NE * 4);
  int* rowB = (int*)alloc((size_t)NE * 4);
  int* colB = (int*)alloc((size_t)NE * 4);
  float* wB = (float*)alloc((size_t)NE * 4);
  int* csr_src = (int*)alloc((size_t)NE * 4);
  int* offsets = (int*)alloc((size_t)(N0 + 1) * 4);
  int* counts = (int*)alloc((size_t)N0 * 4);
  int* fill = (int*)alloc((size_t)N0 * 4);
  float* dinv = (float*)alloc((size_t)N0 * 4);
  float* scoreb = (float*)alloc((size_t)N0 * 4);
  float* ubuf = (float*)alloc((size_t)N0 * 4);
  float* rbuf = (float*)alloc((size_t)N0 * 4);
  int* perm = (int*)alloc((size_t)NB * KP1 * 4);
  int* inv = (int*)alloc((size_t)N0 * 4);
  float* bnsums = (float*)alloc(1024 * 4);
  float* bnss = (float*)alloc(1024 * 4);
  ushort* wt1h = (ushort*)alloc(512 * 512 * 2);
  ushort* wt1l = (ushort*)alloc(512 * 512 * 2);
  ushort* wt2h = (ushort*)alloc(512 * 512 * 2);
  ushort* wt2l = (ushort*)alloc(512 * 512 * 2);
  ushort* wt3h = (ushort*)alloc(256 * 512 * 2);
  ushort* wt3l = (ushort*)alloc(256 * 512 * 2);
  ushort* wt4h = (ushort*)alloc(256 * 256 * 2);
  ushort* wt4l = (ushort*)alloc(256 * 256 * 2);

  const int n1 = NB * KP1;  // 28800
  const int n2 = NB * KP2;  // 17280
  const int n3 = NB * KP3;  // 8640

  auto build_csr_rest = [&](const int* row, const int* col, const float* w, int n) {
    hipMemsetAsync(fill, 0, (size_t)n * 4, stream);
    scan_kernel<<<1, 1024, 0, stream>>>(counts, offsets, dinv, n);
    csr_fill_kernel<<<(NE + 255) / 256, 256, 0, stream>>>(row, col, w, NE, offsets, fill, csr_src);
  };

  auto bn_relu_dots = [&](float* h, int n, int C, const float* g, const float* be,
                          const float* wrel, const float* wroot) {
    hipMemsetAsync(bnsums, 0, 4096, stream);
    size_t n4 = (size_t)n * C / 4;
    int nblk = (int)min((n4 + 255) / 256, (size_t)512);
    bn_stats_kernel<<<nblk, 256, 0, stream>>>(h, n4, C, bnsums);
    bn_finalize_kernel<<<(C + 255) / 256, 256, 0, stream>>>(bnsums, g, be, n, C, bnss);
    bn_dots_kernel<<<(n + 3) / 4, 256, 0, stream>>>(h, bnss, wrel, wroot, ubuf, rbuf, n, C);
  };

  auto gemm = [&](const ushort* ah, const ushort* al, const ushort* bth, const ushort* btl,
                  float* Cout, int M, int K, int N) {
    int mblocks = (M + 127) / 128;
    int nblocks = N / 128;
    gemm_split<<<mblocks * nblocks, 256, 0, stream>>>(ah, al, bth, btl, Cout, M, K, N, mblocks);
  };

  auto pool = [&](const float* h, int n, int C, int npg, int K, const float* pb, int nNext,
                  const int* erow, const int* ecol, const float* ew,
                  int* nrow, int* ncol, float* nw) {
    score_kernel<<<(n + 255) / 256, 256, 0, stream>>>(ubuf, rbuf, offsets, csr_src, pb, scoreb, n);
    topk_radix_kernel<<<NB, 1024, 0, stream>>>(scoreb, npg, K, perm);
    hipMemsetAsync(inv, 0xFF, (size_t)n * 4, stream);
    hipMemsetAsync(counts, 0, (size_t)nNext * 4, stream);
    xnew_split_kernel<<<NB * K, 128, 0, stream>>>(h, scoreb, perm, Ahi, Alo, inv, C);
    edge_remap_count_kernel<<<(NE + 255) / 256, 256, 0, stream>>>(erow, ecol, ew, inv, NE,
                                                                  nrow, ncol, nw, counts);
  };

  // weight transpose+split, x0 split
  wsplit_kernel<<<dim3(512 / 32, 512 / 32), dim3(32, 8), 0, stream>>>(W1, wt1h, wt1l, 512, 512);
  wsplit_kernel<<<dim3(512 / 32, 512 / 32), dim3(32, 8), 0, stream>>>(W2, wt2h, wt2l, 512, 512);
  wsplit_kernel<<<dim3(256 / 32, 512 / 32), dim3(32, 8), 0, stream>>>(W3, wt3h, wt3l, 512, 256);
  wsplit_kernel<<<dim3(256 / 32, 256 / 32), dim3(32, 8), 0, stream>>>(W4, wt4h, wt4l, 256, 256);
  split_kernel<<<4096, 256, 0, stream>>>(x0, Ahi, Alo, (size_t)N0 * 512 / 4);

  // ---------------- Layer 1 ----------------
  hipMemsetAsync(counts, 0, (size_t)N0 * 4, stream);
  edge_count_kernel<<<(NE + 255) / 256, 256, 0, stream>>>(col0, nullptr, NE, counts);
  build_csr_rest(row0, col0, nullptr, N0);
  gemm(Ahi, Alo, wt1h, wt1l, RegA, N0, 512, 512);
  gcn_gather_kernel<<<N0 / 4, 256, 0, stream>>>(RegA, offsets, csr_src, dinv, nullptr,
                                                RegB, 512, N0, NPG0);
  bn_relu_dots(RegB, N0, 512, g1, be1, p1rel, p1root);
  pool(RegB, N0, 512, NPG0, KP1, p1b, n1, row0, col0, nullptr, rowA, colA, wA);

  // ---------------- Layer 2 ----------------
  build_csr_rest(rowA, colA, wA, n1);
  gemm(Ahi, Alo, wt2h, wt2l, RegA, n1, 512, 512);
  gcn_gather_kernel<<<n1 / 4, 256, 0, stream>>>(RegA, offsets, csr_src, dinv, nullptr,
                                                RegB, 512, n1, KP1);
  bn_relu_dots(RegB, n1, 512, g2, be2, p2rel, p2root);
  pool(RegB, n1, 512, KP1, KP2, p2b, n2, rowA, colA, wA, rowB, colB, wB);

  // ---------------- Layer 3 ----------------
  build_csr_rest(rowB, colB, wB, n2);
  gemm(Ahi, Alo, wt3h, wt3l, RegA, n2, 512, 256);
  gcn_gather_kernel<<<n2 / 4, 256, 0, stream>>>(RegA, offsets, csr_src, dinv, nullptr,
                                                RegB, 256, n2, KP2);
  bn_relu_dots(RegB, n2, 256, g3, be3, p3rel, p3root);
  pool(RegB, n2, 256, KP2, KP3, p3b, n3, rowB, colB, wB, rowA, colA, wA);

  // ---------------- Layer 4 ----------------
  build_csr_rest(rowA, colA, wA, n3);
  gemm(Ahi, Alo, wt4h, wt4l, RegA, n3, 256, 256);
  gcn_gather_kernel<<<n3 / 4, 256, 0, stream>>>(RegA, offsets, csr_src, dinv, b4,
                                                RegB, 256, n3, KP3);

  // ---------------- readout ----------------
  final_pool_kernel<<<NB, 256, 0, stream>>>(RegB, out);
  fc_kernel<<<NB, 64, 0, stream>>>(out + 8, fcW, fcb, out);
}

// Round 7
// 914.569 us; speedup vs baseline: 1.1733x; 1.1733x over previous
//
#include <hip/hip_runtime.h>
#include <cstdint>
#include <cstddef>

#define NB 8
#define NPG0 6000
#define N0 48000
#define NE 384000
#define KP1 3600
#define KP2 2160
#define KP3 1080

typedef __attribute__((ext_vector_type(8))) short short8;
typedef __attribute__((ext_vector_type(4))) float f32x4;
typedef __attribute__((ext_vector_type(4))) unsigned int u32x4;

__device__ inline ushort f2bf(float v) {
  unsigned u = __float_as_uint(v);
  u += 0x7FFF + ((u >> 16) & 1);
  return (ushort)(u >> 16);
}
__device__ inline float bf2f(ushort h) { return __uint_as_float(((unsigned)h) << 16); }

__device__ __forceinline__ void glds16(const void* g, void* l) {
  __builtin_amdgcn_global_load_lds(
      (const __attribute__((address_space(1))) unsigned int*)g,
      (__attribute__((address_space(3))) unsigned int*)l, 16, 0, 0);
}

// ============ split fp32 -> bf16 hi/lo ============
__global__ void split_kernel(const float* __restrict__ x, ushort* __restrict__ hi,
                             ushort* __restrict__ lo, size_t n4) {
  size_t i = (size_t)blockIdx.x * blockDim.x + threadIdx.x;
  size_t stride = (size_t)gridDim.x * blockDim.x;
  for (; i < n4; i += stride) {
    float4 v = ((const float4*)x)[i];
    ushort4 h, l;
    h.x = f2bf(v.x); l.x = f2bf(v.x - bf2f(h.x));
    h.y = f2bf(v.y); l.y = f2bf(v.y - bf2f(h.y));
    h.z = f2bf(v.z); l.z = f2bf(v.z - bf2f(h.z));
    h.w = f2bf(v.w); l.w = f2bf(v.w - bf2f(h.w));
    ((ushort4*)hi)[i] = h;
    ((ushort4*)lo)[i] = l;
  }
}

// ============ W[K,N] fp32 -> WT hi/lo bf16 [N,K] ============
__global__ void wsplit_kernel(const float* __restrict__ W, ushort* __restrict__ hiT,
                              ushort* __restrict__ loT, int K, int N) {
  __shared__ float tile[32][33];
  int k0 = blockIdx.y * 32, n0 = blockIdx.x * 32;
  int tx = threadIdx.x;
  for (int dy = threadIdx.y; dy < 32; dy += 8)
    tile[dy][tx] = W[(size_t)(k0 + dy) * N + n0 + tx];
  __syncthreads();
  for (int dy = threadIdx.y; dy < 32; dy += 8) {
    float v = tile[tx][dy];
    ushort h = f2bf(v);
    ushort l = f2bf(v - bf2f(h));
    hiT[(size_t)(n0 + dy) * K + k0 + tx] = h;
    loT[(size_t)(n0 + dy) * K + k0 + tx] = l;
  }
}

// ============ GEMM: split-bf16 MFMA, 128x128 tile, BK=32, global_load_lds ====
__global__ __launch_bounds__(256) void gemm_split(
    const ushort* __restrict__ Ahi, const ushort* __restrict__ Alo,
    const ushort* __restrict__ BThi, const ushort* __restrict__ BTlo,
    float* __restrict__ C, int M, int K, int N, int mblocks) {
  __shared__ u32x4 lds4[4096];  // 2 x 32KB
  const int tid = threadIdx.x;
  const int lane = tid & 63;
  const int w = tid >> 6;       // wave id = staging region
  const int mblk = blockIdx.x % mblocks;
  const int nblk = blockIdx.x / mblocks;
  const int bm = mblk * 128, bn = nblk * 128;
  const int wr = w >> 1, wc = w & 1;

  const ushort* srcp[8];
  {
    const ushort* base = (w == 0) ? Ahi : (w == 1) ? Alo : (w == 2) ? BThi : BTlo;
    #pragma unroll
    for (int i = 0; i < 8; ++i) {
      int r = i * 16 + (lane >> 2);
      int swz = (r & 3) ^ ((r >> 2) & 3);
      int pcs = (lane & 3) ^ swz;
      int grow = (w < 2) ? min(bm + r, M - 1) : (bn + r);
      srcp[i] = base + (size_t)grow * K + pcs * 8;
    }
  }

  f32x4 acc[4][4];
#pragma unroll
  for (int m = 0; m < 4; ++m)
#pragma unroll
    for (int n = 0; n < 4; ++n) acc[m][n] = (f32x4){0.f, 0.f, 0.f, 0.f};

  const int nk = K >> 5;
  const int kb = lane >> 4;
  const int l15 = lane & 15;

#pragma unroll
  for (int i = 0; i < 8; ++i) glds16(srcp[i], &lds4[w * 512 + i * 64]);
  __syncthreads();

  int cur = 0;
  for (int t = 0; t < nk; ++t) {
    if (t + 1 < nk) {
      int nb = (cur ^ 1) * 2048;
#pragma unroll
      for (int i = 0; i < 8; ++i)
        glds16(srcp[i] + (size_t)(t + 1) * 32, &lds4[nb + w * 512 + i * 64]);
    }
    const int bb = cur * 2048;
    short8 bh[4], bl[4];
#pragma unroll
    for (int n = 0; n < 4; ++n) {
      int rB = wc * 64 + n * 16 + l15;
      int swz = (rB & 3) ^ ((rB >> 2) & 3);
      int ch = rB * 4 + (kb ^ swz);
      bh[n] = *(const short8*)&lds4[bb + 1024 + ch];
      bl[n] = *(const short8*)&lds4[bb + 1536 + ch];
    }
#pragma unroll
    for (int m = 0; m < 4; ++m) {
      int rA = wr * 64 + m * 16 + l15;
      int swz = (rA & 3) ^ ((rA >> 2) & 3);
      int ch = rA * 4 + (kb ^ swz);
      short8 ah = *(const short8*)&lds4[bb + ch];
      short8 al = *(const short8*)&lds4[bb + 512 + ch];
#pragma unroll
      for (int n = 0; n < 4; ++n) {
        acc[m][n] = __builtin_amdgcn_mfma_f32_16x16x32_bf16(ah, bh[n], acc[m][n], 0, 0, 0);
        acc[m][n] = __builtin_amdgcn_mfma_f32_16x16x32_bf16(ah, bl[n], acc[m][n], 0, 0, 0);
        acc[m][n] = __builtin_amdgcn_mfma_f32_16x16x32_bf16(al, bh[n], acc[m][n], 0, 0, 0);
      }
    }
    __syncthreads();
    cur ^= 1;
  }

#pragma unroll
  for (int m = 0; m < 4; ++m) {
    int gr0 = bm + wr * 64 + m * 16 + ((lane >> 4) << 2);
#pragma unroll
    for (int j = 0; j < 4; ++j) {
      int gr = gr0 + j;
      if (gr < M) {
#pragma unroll
        for (int n = 0; n < 4; ++n) {
          C[(size_t)gr * N + bn + wc * 64 + n * 16 + (lane & 15)] = acc[m][n][j];
        }
      }
    }
  }
}

// ---------------- CSR build ----------------
__global__ void edge_count_kernel(const int* __restrict__ col, const float* __restrict__ w,
                                  int E, int* __restrict__ counts) {
  int i = blockIdx.x * blockDim.x + threadIdx.x;
  if (i >= E) return;
  if (w && !(w[i] > 0.f)) return;
  atomicAdd(&counts[col[i]], 1);
}

// ---- multi-block scan: phase1 block sums, phase2 scan of block sums, phase3 emit ----
__global__ __launch_bounds__(256) void scan_phase1(const int* __restrict__ counts,
                                                   int* __restrict__ bsums, int n) {
  __shared__ int wt[4];
  int b = blockIdx.x, tid = threadIdx.x;
  int base = b * 1024 + tid * 4;
  int s = 0;
  if (base + 4 <= n) {
    int4 v = *(const int4*)&counts[base];
    s = v.x + v.y + v.z + v.w;
  } else {
    for (int j = 0; j < 4; ++j) {
      int idx = base + j;
      if (idx < n) s += counts[idx];
    }
  }
  int lane = tid & 63, wid = tid >> 6;
  int v = s;
  for (int off = 1; off < 64; off <<= 1) {
    int t = __shfl_up(v, off);
    if (lane >= off) v += t;
  }
  if (lane == 63) wt[wid] = v;
  __syncthreads();
  if (tid == 0) bsums[b] = wt[0] + wt[1] + wt[2] + wt[3];
}

// single wave: exclusive-scan bsums in place (nb <= 64), write offsets[n] = total
__global__ void scan_phase2(int* __restrict__ bsums, int nb,
                            int* __restrict__ offsets, int n) {
  int tid = threadIdx.x;  // 64
  int orig = (tid < nb) ? bsums[tid] : 0;
  int v = orig;
  for (int off = 1; off < 64; off <<= 1) {
    int t = __shfl_up(v, off);
    if (tid >= off) v += t;
  }
  if (tid < nb) bsums[tid] = v - orig;
  if (tid == 63) offsets[n] = v;
}

__global__ __launch_bounds__(256) void scan_phase3(const int* __restrict__ counts,
                                                   const int* __restrict__ bsums_excl,
                                                   int* __restrict__ offsets,
                                                   float* __restrict__ dinv, int n) {
  __shared__ int wt[4];
  int b = blockIdx.x, tid = threadIdx.x;
  int base = b * 1024 + tid * 4;
  int c[4];
  int s = 0;
  if (base + 4 <= n) {
    int4 v = *(const int4*)&counts[base];
    c[0] = v.x; c[1] = v.y; c[2] = v.z; c[3] = v.w;
    s = v.x + v.y + v.z + v.w;
  } else {
#pragma unroll
    for (int j = 0; j < 4; ++j) {
      int idx = base + j;
      c[j] = (idx < n) ? counts[idx] : 0;
      s += c[j];
    }
  }
  int lane = tid & 63, wid = tid >> 6;
  int v = s;
  for (int off = 1; off < 64; off <<= 1) {
    int t = __shfl_up(v, off);
    if (lane >= off) v += t;
  }
  if (lane == 63) wt[wid] = v;
  __syncthreads();
  int woff = 0;
  for (int q = 0; q < wid; ++q) woff += wt[q];
  int excl = (v - s) + woff + bsums_excl[b];
#pragma unroll
  for (int j = 0; j < 4; ++j) {
    int idx = base + j;
    if (idx < n) {
      offsets[idx] = excl;
      dinv[idx] = (c[j] > 0) ? rsqrtf((float)c[j]) : 0.f;
      excl += c[j];
    }
  }
}

__global__ void csr_fill_kernel(const int* __restrict__ row, const int* __restrict__ col,
                                const float* __restrict__ w, int E,
                                const int* __restrict__ offsets, int* __restrict__ fill,
                                int* __restrict__ csr_src) {
  int i = blockIdx.x * blockDim.x + threadIdx.x;
  if (i >= E) return;
  if (w && !(w[i] > 0.f)) return;
  int c = col[i];
  int pos = offsets[c] + atomicAdd(&fill[c], 1);
  csr_src[pos] = row[i];
}

// ---------------- GCN gather: wave per node, graph-per-XCD swizzle ----------------
__global__ __launch_bounds__(256) void gcn_gather_kernel(
    const float* __restrict__ G, const int* __restrict__ offsets,
    const int* __restrict__ csr_src, const float* __restrict__ dinv,
    const float* __restrict__ bias, float* __restrict__ out, int C, int n, int npg) {
  int wid = threadIdx.x >> 6, lane = threadIdx.x & 63;
  int g = blockIdx.x & 7;
  int local = blockIdx.x >> 3;
  int t = g * npg + local * 4 + wid;
  if (t >= n) return;
  int beg = offsets[t], end = offsets[t + 1];
  float dt = dinv[t];
  bool two = (C == 512);
  float4 acc0 = make_float4(0.f, 0.f, 0.f, 0.f);
  float4 acc1 = make_float4(0.f, 0.f, 0.f, 0.f);
  int e = beg;
  for (; e + 2 <= end; e += 2) {
    int s0 = csr_src[e], s1 = csr_src[e + 1];
    float d0 = dinv[s0], d1 = dinv[s1];
    const float4* h0 = (const float4*)(G + (size_t)s0 * C);
    const float4* h1 = (const float4*)(G + (size_t)s1 * C);
    float4 a0 = h0[lane];
    float4 b0 = h1[lane];
    acc0.x += d0 * a0.x; acc0.y += d0 * a0.y; acc0.z += d0 * a0.z; acc0.w += d0 * a0.w;
    acc0.x += d1 * b0.x; acc0.y += d1 * b0.y; acc0.z += d1 * b0.z; acc0.w += d1 * b0.w;
    if (two) {
      float4 a1 = h0[lane + 64];
      float4 b1 = h1[lane + 64];
      acc1.x += d0 * a1.x; acc1.y += d0 * a1.y; acc1.z += d0 * a1.z; acc1.w += d0 * a1.w;
      acc1.x += d1 * b1.x; acc1.y += d1 * b1.y; acc1.z += d1 * b1.z; acc1.w += d1 * b1.w;
    }
  }
  if (e < end) {
    int s0 = csr_src[e];
    float d0 = dinv[s0];
    const float4* h0 = (const float4*)(G + (size_t)s0 * C);
    float4 a0 = h0[lane];
    acc0.x += d0 * a0.x; acc0.y += d0 * a0.y; acc0.z += d0 * a0.z; acc0.w += d0 * a0.w;
    if (two) {
      float4 a1 = h0[lane + 64];
      acc1.x += d0 * a1.x; acc1.y += d0 * a1.y; acc1.z += d0 * a1.z; acc1.w += d0 * a1.w;
    }
  }
  float4* op = (float4*)(out + (size_t)t * C);
  float4 b0 = bias ? ((const float4*)bias)[lane] : make_float4(0.f, 0.f, 0.f, 0.f);
  op[lane] = make_float4(dt * acc0.x + b0.x, dt * acc0.y + b0.y,
                         dt * acc0.z + b0.z, dt * acc0.w + b0.w);
  if (two) {
    op[lane + 64] = make_float4(dt * acc1.x, dt * acc1.y, dt * acc1.z, dt * acc1.w);
  }
}

// ---------------- BatchNorm stats: grid-stride float4 streaming ----------------
__global__ __launch_bounds__(256) void bn_stats_kernel(
    const float* __restrict__ h, size_t n4, int C, float* __restrict__ sums) {
  __shared__ float ls[1024];
  for (int i = threadIdx.x; i < 2 * C; i += 256) ls[i] = 0.f;
  __syncthreads();
  const int c0 = (threadIdx.x * 4) & (C - 1);
  float s0 = 0.f, s1 = 0.f, s2 = 0.f, s3 = 0.f;
  float q0 = 0.f, q1 = 0.f, q2 = 0.f, q3 = 0.f;
  size_t i = (size_t)blockIdx.x * 256 + threadIdx.x;
  const size_t stride = (size_t)gridDim.x * 256;
  for (; i < n4; i += stride) {
    float4 v = ((const float4*)h)[i];
    s0 += v.x; q0 += v.x * v.x;
    s1 += v.y; q1 += v.y * v.y;
    s2 += v.z; q2 += v.z * v.z;
    s3 += v.w; q3 += v.w * v.w;
  }
  atomicAdd(&ls[c0 + 0], s0); atomicAdd(&ls[C + c0 + 0], q0);
  atomicAdd(&ls[c0 + 1], s1); atomicAdd(&ls[C + c0 + 1], q1);
  atomicAdd(&ls[c0 + 2], s2); atomicAdd(&ls[C + c0 + 2], q2);
  atomicAdd(&ls[c0 + 3], s3); atomicAdd(&ls[C + c0 + 3], q3);
  __syncthreads();
  for (int j = threadIdx.x; j < 2 * C; j += 256) atomicAdd(&sums[j], ls[j]);
}

__global__ void bn_finalize_kernel(const float* __restrict__ sums,
                                   const float* __restrict__ g,
                                   const float* __restrict__ be,
                                   int n, int C, float* __restrict__ ss) {
  int c = blockIdx.x * blockDim.x + threadIdx.x;
  if (c >= C) return;
  float inv_n = 1.0f / (float)n;
  float mean = sums[c] * inv_n;
  float var = sums[C + c] * inv_n - mean * mean;
  var = fmaxf(var, 0.f);
  float sc = g[c] * rsqrtf(var + 1e-5f);
  ss[c] = sc;
  ss[C + c] = be[c] - mean * sc;
}

// fused BN-apply + relu + pool dot products (wave per row)
__global__ __launch_bounds__(256) void bn_dots_kernel(
    float* __restrict__ h, const float* __restrict__ ss,
    const float* __restrict__ wrel, const float* __restrict__ wroot,
    float* __restrict__ u, float* __restrict__ rr, int n, int C) {
  int wid = threadIdx.x >> 6, lane = threadIdx.x & 63;
  int v = blockIdx.x * 4 + wid;
  if (v >= n) return;
  float4* hr = (float4*)(h + (size_t)v * C);
  int nf4 = C >> 2;
  float su = 0.f, sr = 0.f;
  for (int q = lane; q < nf4; q += 64) {
    float4 x = hr[q];
    int c = q << 2;
    float4 sc = *(const float4*)&ss[c];
    float4 sh = *(const float4*)&ss[C + c];
    x.x = fmaxf(fmaf(x.x, sc.x, sh.x), 0.f);
    x.y = fmaxf(fmaf(x.y, sc.y, sh.y), 0.f);
    x.z = fmaxf(fmaf(x.z, sc.z, sh.z), 0.f);
    x.w = fmaxf(fmaf(x.w, sc.w, sh.w), 0.f);
    hr[q] = x;
    float4 w1 = *(const float4*)&wrel[c];
    float4 w2 = *(const float4*)&wroot[c];
    su += x.x * w1.x + x.y * w1.y + x.z * w1.z + x.w * w1.w;
    sr += x.x * w2.x + x.y * w2.y + x.z * w2.z + x.w * w2.w;
  }
  for (int off = 32; off > 0; off >>= 1) {
    su += __shfl_down(su, off);
    sr += __shfl_down(sr, off);
  }
  if (lane == 0) {
    u[v] = su;
    rr[v] = sr;
  }
}

__global__ void score_kernel(const float* __restrict__ u, const float* __restrict__ rr,
                             const int* __restrict__ offsets, const int* __restrict__ csr_src,
                             const float* __restrict__ pb, float* __restrict__ score, int n) {
  int i = blockIdx.x * blockDim.x + threadIdx.x;
  if (i >= n) return;
  float s = rr[i] + pb[0];
  int beg = offsets[i], end = offsets[i + 1];
  for (int e = beg; e < end; ++e) s += u[csr_src[e]];
  score[i] = s;
}

// ---------------- exact top-k via 4-pass radix select (per graph) ----------------
__global__ __launch_bounds__(1024) void topk_radix_kernel(
    const float* __restrict__ score, int npg, int K, int* __restrict__ perm) {
  __shared__ unsigned sbuf[8192];
  __shared__ int tieL[6000];
  __shared__ int hist[256];
  __shared__ int wps[4];
  __shared__ unsigned sPref;
  __shared__ int sKrem, sAbove, sSel, sTie;
  int g = blockIdx.x;
  int tid = threadIdx.x;
  for (int i = tid; i < npg; i += 1024) {
    unsigned u = __float_as_uint(score[g * npg + i]);
    sbuf[i] = (u >> 31) ? ~u : (u | 0x80000000u);
  }
  if (tid == 0) { sPref = 0; sKrem = K; sAbove = 0; sSel = 0; sTie = 0; }
  __syncthreads();

  for (int pass = 0; pass < 4; ++pass) {
    int shift = 24 - 8 * pass;
    if (tid < 256) hist[tid] = 0;
    unsigned prefLoc = sPref;
    int kRemLoc = sKrem;
    __syncthreads();
    for (int i = tid; i < npg; i += 1024) {
      unsigned k = sbuf[i];
      if (pass == 0 || (k >> (shift + 8)) == prefLoc)
        atomicAdd(&hist[(k >> shift) & 255], 1);
    }
    __syncthreads();
    int v = 0, a = 0;
    if (tid < 256) {
      a = hist[255 - tid];
      v = a;
      int lane = tid & 63;
      for (int off = 1; off < 64; off <<= 1) {
        int t2 = __shfl_up(v, off);
        if (lane >= off) v += t2;
      }
      if (lane == 63) wps[tid >> 6] = v;
    }
    __syncthreads();
    if (tid < 256) {
      int w4 = tid >> 6;
      int incl = v;
      for (int q = 0; q < w4; ++q) incl += wps[q];
      int gt = incl - a;
      if (gt < kRemLoc && kRemLoc <= incl) {
        int d = 255 - tid;
        sPref = (prefLoc << 8) | (unsigned)d;
        sAbove += gt;
        sKrem = kRemLoc - gt;
      }
    }
    __syncthreads();
  }

  unsigned T = sPref;
  int above = sAbove;
  for (int i = tid; i < npg; i += 1024) {
    unsigned k = sbuf[i];
    if (k > T) {
      int p = atomicAdd(&sSel, 1);
      perm[g * K + p] = g * npg + i;
    } else if (k == T) {
      int p = atomicAdd(&sTie, 1);
      tieL[p] = i;
    }
  }
  __syncthreads();
  int r = sKrem, tc = sTie;
  if (r == tc) {
    for (int j = tid; j < r; j += 1024) perm[g * K + above + j] = g * npg + tieL[j];
  } else {
    int p2 = 1;
    while (p2 < tc) p2 <<= 1;
    for (int i = tid; i < p2; i += 1024) sbuf[i] = (i < tc) ? (unsigned)tieL[i] : 0xFFFFFFFFu;
    __syncthreads();
    for (int k2 = 2; k2 <= p2; k2 <<= 1) {
      for (int j = k2 >> 1; j > 0; j >>= 1) {
        for (int i = tid; i < p2; i += 1024) {
          int l = i ^ j;
          if (l > i) {
            unsigned a2 = sbuf[i], b2 = sbuf[l];
            bool up = ((i & k2) == 0);
            if (up ? (a2 > b2) : (a2 < b2)) { sbuf[i] = b2; sbuf[l] = a2; }
          }
        }
        __syncthreads();
      }
    }
    for (int j = tid; j < r; j += 1024) perm[g * K + above + j] = g * npg + (int)sbuf[j];
  }
}

// pooled x -> bf16 hi/lo + inv map (fused)
__global__ void xnew_split_kernel(const float* __restrict__ h, const float* __restrict__ score,
                                  const int* __restrict__ perm, ushort* __restrict__ xhi,
                                  ushort* __restrict__ xlo, int* __restrict__ inv, int C) {
  int i = blockIdx.x;
  int old = perm[i];
  if (threadIdx.x == 0) inv[old] = i;
  float tv = tanhf(score[old]);
  const float4* src = (const float4*)(h + (size_t)old * C);
  int c4 = C >> 2;
  for (int c = threadIdx.x; c < c4; c += blockDim.x) {
    float4 v = src[c];
    v.x *= tv; v.y *= tv; v.z *= tv; v.w *= tv;
    ushort4 hh, ll;
    hh.x = f2bf(v.x); ll.x = f2bf(v.x - bf2f(hh.x));
    hh.y = f2bf(v.y); ll.y = f2bf(v.y - bf2f(hh.y));
    hh.z = f2bf(v.z); ll.z = f2bf(v.z - bf2f(hh.z));
    hh.w = f2bf(v.w); ll.w = f2bf(v.w - bf2f(hh.w));
    ((ushort4*)(xhi + (size_t)i * C))[c] = hh;
    ((ushort4*)(xlo + (size_t)i * C))[c] = ll;
  }
}

// fused: remap edges + count next-layer in-degrees
__global__ void edge_remap_count_kernel(const int* __restrict__ row, const int* __restrict__ col,
                                        const float* __restrict__ w, const int* __restrict__ inv,
                                        int E, int* __restrict__ nrow, int* __restrict__ ncol,
                                        float* __restrict__ nw, int* __restrict__ counts) {
  int i = blockIdx.x * blockDim.x + threadIdx.x;
  if (i >= E) return;
  float wv = w ? w[i] : 1.f;
  int nr = inv[row[i]];
  int nc = inv[col[i]];
  bool valid = (nr >= 0) && (nc >= 0) && (wv > 0.f);
  nrow[i] = valid ? nr : 0;
  ncol[i] = valid ? nc : 0;
  nw[i] = valid ? wv : 0.f;
  if (valid) atomicAdd(&counts[nc], 1);
}

// ---------------- readout ----------------
__global__ void final_pool_kernel(const float* __restrict__ h, float* __restrict__ dout) {
  int g = blockIdx.x;
  int c = threadIdx.x;  // 256
  const float* base = h + ((size_t)g * KP3) * 256 + c;
  float mx = -3.402823466e38f, sm = 0.f;
  for (int r = 0; r < KP3; ++r) {
    float v = base[(size_t)r * 256];
    mx = fmaxf(mx, v);
    sm += v;
  }
  dout[8 + g * 512 + c] = mx;
  dout[8 + g * 512 + 256 + c] = sm * (1.0f / (float)KP3);
}

__global__ void fc_kernel(const float* __restrict__ feat, const float* __restrict__ fcW,
                          const float* __restrict__ fcb, float* __restrict__ dout) {
  int g = blockIdx.x;
  int lane = threadIdx.x;  // 64
  float s = 0.f;
  for (int c = lane; c < 512; c += 64) s += feat[g * 512 + c] * fcW[c];
  for (int off = 32; off > 0; off >>= 1) s += __shfl_down(s, off);
  if (lane == 0) dout[g] = s + fcb[0];
}

// ---------------- host ----------------
static inline size_t alignup(size_t x) { return (x + 255) & ~(size_t)255; }

extern "C" void kernel_launch(void* const* d_in, const int* in_sizes, int n_in,
                              void* d_out, int out_size, void* d_ws, size_t ws_size,
                              hipStream_t stream) {
  (void)in_sizes; (void)n_in; (void)out_size; (void)ws_size;
  const float* x0 = (const float*)d_in[0];
  const int* ei = (const int*)d_in[1];
  const int* row0 = ei;
  const int* col0 = ei + NE;
  const float* W1 = (const float*)d_in[2];
  const float* g1 = (const float*)d_in[4];
  const float* be1 = (const float*)d_in[5];
  const float* p1rel = (const float*)d_in[6];
  const float* p1root = (const float*)d_in[7];
  const float* p1b = (const float*)d_in[8];
  const float* W2 = (const float*)d_in[9];
  const float* g2 = (const float*)d_in[11];
  const float* be2 = (const float*)d_in[12];
  const float* p2rel = (const float*)d_in[13];
  const float* p2root = (const float*)d_in[14];
  const float* p2b = (const float*)d_in[15];
  const float* W3 = (const float*)d_in[16];
  const float* g3 = (const float*)d_in[18];
  const float* be3 = (const float*)d_in[19];
  const float* p3rel = (const float*)d_in[20];
  const float* p3root = (const float*)d_in[21];
  const float* p3b = (const float*)d_in[22];
  const float* W4 = (const float*)d_in[23];
  const float* b4 = (const float*)d_in[24];
  const float* fcW = (const float*)d_in[25];
  const float* fcb = (const float*)d_in[26];
  float* out = (float*)d_out;

  char* ws = (char*)d_ws;
  size_t off = 0;
  auto alloc = [&](size_t bytes) {
    char* p = ws + off;
    off = alignup(off + bytes);
    return p;
  };
  float* RegA = (float*)alloc((size_t)N0 * 512 * 4);
  float* RegB = (float*)alloc((size_t)N0 * 512 * 4);
  ushort* Ahi = (ushort*)alloc((size_t)N0 * 512 * 2);
  ushort* Alo = (ushort*)alloc((size_t)N0 * 512 * 2);
  int* rowA = (int*)alloc((size_t)NE * 4);
  int* colA = (int*)alloc((size_t)NE * 4);
  float* wA = (float*)alloc((size_t)NE * 4);
  int* rowB = (int*)alloc((size_t)NE * 4);
  int* colB = (int*)alloc((size_t)NE * 4);
  float* wB = (float*)alloc((size_t)NE * 4);
  int* csr_src = (int*)alloc((size_t)NE * 4);
  int* offsets = (int*)alloc((size_t)(N0 + 1) * 4);
  int* counts = (int*)alloc((size_t)N0 * 4);
  int* fill = (int*)alloc((size_t)N0 * 4);
  float* dinv = (float*)alloc((size_t)N0 * 4);
  float* scoreb = (float*)alloc((size_t)N0 * 4);
  float* ubuf = (float*)alloc((size_t)N0 * 4);
  float* rbuf = (float*)alloc((size_t)N0 * 4);
  int* perm = (int*)alloc((size_t)NB * KP1 * 4);
  int* inv = (int*)alloc((size_t)N0 * 4);
  int* bsums = (int*)alloc(64 * 4);
  float* bnsums = (float*)alloc(1024 * 4);
  float* bnss = (float*)alloc(1024 * 4);
  ushort* wt1h = (ushort*)alloc(512 * 512 * 2);
  ushort* wt1l = (ushort*)alloc(512 * 512 * 2);
  ushort* wt2h = (ushort*)alloc(512 * 512 * 2);
  ushort* wt2l = (ushort*)alloc(512 * 512 * 2);
  ushort* wt3h = (ushort*)alloc(256 * 512 * 2);
  ushort* wt3l = (ushort*)alloc(256 * 512 * 2);
  ushort* wt4h = (ushort*)alloc(256 * 256 * 2);
  ushort* wt4l = (ushort*)alloc(256 * 256 * 2);

  const int n1 = NB * KP1;  // 28800
  const int n2 = NB * KP2;  // 17280
  const int n3 = NB * KP3;  // 8640

  auto build_csr_rest = [&](const int* row, const int* col, const float* w, int n) {
    hipMemsetAsync(fill, 0, (size_t)n * 4, stream);
    int nb = (n + 1023) / 1024;
    scan_phase1<<<nb, 256, 0, stream>>>(counts, bsums, n);
    scan_phase2<<<1, 64, 0, stream>>>(bsums, nb, offsets, n);
    scan_phase3<<<nb, 256, 0, stream>>>(counts, bsums, offsets, dinv, n);
    csr_fill_kernel<<<(NE + 255) / 256, 256, 0, stream>>>(row, col, w, NE, offsets, fill, csr_src);
  };

  auto bn_relu_dots = [&](float* h, int n, int C, const float* g, const float* be,
                          const float* wrel, const float* wroot) {
    hipMemsetAsync(bnsums, 0, 4096, stream);
    size_t n4 = (size_t)n * C / 4;
    int nblk = (int)min((n4 + 255) / 256, (size_t)512);
    bn_stats_kernel<<<nblk, 256, 0, stream>>>(h, n4, C, bnsums);
    bn_finalize_kernel<<<(C + 255) / 256, 256, 0, stream>>>(bnsums, g, be, n, C, bnss);
    bn_dots_kernel<<<(n + 3) / 4, 256, 0, stream>>>(h, bnss, wrel, wroot, ubuf, rbuf, n, C);
  };

  auto gemm = [&](const ushort* ah, const ushort* al, const ushort* bth, const ushort* btl,
                  float* Cout, int M, int K, int N) {
    int mblocks = (M + 127) / 128;
    int nblocks = N / 128;
    gemm_split<<<mblocks * nblocks, 256, 0, stream>>>(ah, al, bth, btl, Cout, M, K, N, mblocks);
  };

  auto pool = [&](const float* h, int n, int C, int npg, int K, const float* pb, int nNext,
                  const int* erow, const int* ecol, const float* ew,
                  int* nrow, int* ncol, float* nw) {
    score_kernel<<<(n + 255) / 256, 256, 0, stream>>>(ubuf, rbuf, offsets, csr_src, pb, scoreb, n);
    topk_radix_kernel<<<NB, 1024, 0, stream>>>(scoreb, npg, K, perm);
    hipMemsetAsync(inv, 0xFF, (size_t)n * 4, stream);
    hipMemsetAsync(counts, 0, (size_t)nNext * 4, stream);
    xnew_split_kernel<<<NB * K, 128, 0, stream>>>(h, scoreb, perm, Ahi, Alo, inv, C);
    edge_remap_count_kernel<<<(NE + 255) / 256, 256, 0, stream>>>(erow, ecol, ew, inv, NE,
                                                                  nrow, ncol, nw, counts);
  };

  // weight transpose+split, x0 split
  wsplit_kernel<<<dim3(512 / 32, 512 / 32), dim3(32, 8), 0, stream>>>(W1, wt1h, wt1l, 512, 512);
  wsplit_kernel<<<dim3(512 / 32, 512 / 32), dim3(32, 8), 0, stream>>>(W2, wt2h, wt2l, 512, 512);
  wsplit_kernel<<<dim3(256 / 32, 512 / 32), dim3(32, 8), 0, stream>>>(W3, wt3h, wt3l, 512, 256);
  wsplit_kernel<<<dim3(256 / 32, 256 / 32), dim3(32, 8), 0, stream>>>(W4, wt4h, wt4l, 256, 256);
  split_kernel<<<4096, 256, 0, stream>>>(x0, Ahi, Alo, (size_t)N0 * 512 / 4);

  // ---------------- Layer 1 ----------------
  hipMemsetAsync(counts, 0, (size_t)N0 * 4, stream);
  edge_count_kernel<<<(NE + 255) / 256, 256, 0, stream>>>(col0, nullptr, NE, counts);
  build_csr_rest(row0, col0, nullptr, N0);
  gemm(Ahi, Alo, wt1h, wt1l, RegA, N0, 512, 512);
  gcn_gather_kernel<<<N0 / 4, 256, 0, stream>>>(RegA, offsets, csr_src, dinv, nullptr,
                                                RegB, 512, N0, NPG0);
  bn_relu_dots(RegB, N0, 512, g1, be1, p1rel, p1root);
  pool(RegB, N0, 512, NPG0, KP1, p1b, n1, row0, col0, nullptr, rowA, colA, wA);

  // ---------------- Layer 2 ----------------
  build_csr_rest(rowA, colA, wA, n1);
  gemm(Ahi, Alo, wt2h, wt2l, RegA, n1, 512, 512);
  gcn_gather_kernel<<<n1 / 4, 256, 0, stream>>>(RegA, offsets, csr_src, dinv, nullptr,
                                                RegB, 512, n1, KP1);
  bn_relu_dots(RegB, n1, 512, g2, be2, p2rel, p2root);
  pool(RegB, n1, 512, KP1, KP2, p2b, n2, rowA, colA, wA, rowB, colB, wB);

  // ---------------- Layer 3 ----------------
  build_csr_rest(rowB, colB, wB, n2);
  gemm(Ahi, Alo, wt3h, wt3l, RegA, n2, 512, 256);
  gcn_gather_kernel<<<n2 / 4, 256, 0, stream>>>(RegA, offsets, csr_src, dinv, nullptr,
                                                RegB, 256, n2, KP2);
  bn_relu_dots(RegB, n2, 256, g3, be3, p3rel, p3root);
  pool(RegB, n2, 256, KP2, KP3, p3b, n3, rowB, colB, wB, rowA, colA, wA);

  // ---------------- Layer 4 ----------------
  build_csr_rest(rowA, colA, wA, n3);
  gemm(Ahi, Alo, wt4h, wt4l, RegA, n3, 256, 256);
  gcn_gather_kernel<<<n3 / 4, 256, 0, stream>>>(RegA, offsets, csr_src, dinv, b4,
                                                RegB, 256, n3, KP3);

  // ---------------- readout ----------------
  final_pool_kernel<<<NB, 256, 0, stream>>>(RegB, out);
  fc_kernel<<<NB, 64, 0, stream>>>(out + 8, fcW, fcb, out);
}